// Round 3
// baseline (336.465 us; speedup 1.0000x reference)
//
#include <hip/hip_runtime.h>

// Fused tensor-field + 3-layer MLP for MI355X (gfx950). Round 3.
//
// R2 post-mortem: 2 px/thread spilled (VGPR_Count=108 vs ~192 live floats,
// WRITE_SIZE 21MB vs 8.4MB stored, VALU cycles 3.2x the 55us FMA floor).
// Fixes: (1) 1 px/thread, __launch_bounds__(256,4) -> 128-VGPR cap,
// 4 blocks/CU exactly (grid 1024), 4 waves/SIMD latency hiding.
// (2) Packed fp32: express MLP j-dim as float2 ext-vectors with
// __builtin_elementwise_fma -> llvm.fma.v2f32 -> v_pk_fma_f32 (2 FMA/lane/instr).
// Weights fetched as uniform float2 (s_load pairs). Degrades to scalar FMA
// if the backend declines to pack -- no correctness risk.

typedef float f32x2 __attribute__((ext_vector_type(2)));
typedef float f32x4 __attribute__((ext_vector_type(4)));

constexpr int NPIX = 512 * 512;

__global__ __launch_bounds__(256, 4) void field_mlp_kernel(
    const float* __restrict__ z,        // [8]
    const float* __restrict__ data,     // [512,512,32]
    const float* __restrict__ z_data,   // [64,32]
    const float* __restrict__ lerp_w,   // [NPIX,2]
    const int* __restrict__ x0a, const int* __restrict__ y0a,
    const int* __restrict__ x1a, const int* __restrict__ y1a,
    const float* __restrict__ W1, const float* __restrict__ b1,
    const float* __restrict__ W2, const float* __restrict__ b2,
    const float* __restrict__ W3, const float* __restrict__ b3,
    float* __restrict__ out)            // [8,1,512,512]
{
    __shared__ float zf_lds[8][32];
    const int tid = threadIdx.x;

    // Cooperative z-feature: 256 threads cover 8 batches x 32 feats.
    {
        const int b = tid >> 5;
        const int i = tid & 31;
        const float zn = 63.0f * z[b];        // Z_MIN=0, Z_MAX=1
        int z0 = (int)zn;
        z0 = max(0, min(z0, 63));
        const int z1 = min(z0 + 1, 63);
        const float zl = zn - truncf(zn);
        zf_lds[b][i] = z_data[z0 * 32 + i] * (1.0f - zl) + z_data[z1 * 32 + i] * zl;
    }
    __syncthreads();

    const int p = blockIdx.x * 256 + tid;

    // ---- Bilinear gather: 4 corners x 32 feats, float4 vector math ----
    f32x4 fq[8];                              // 32 feats as 8x float4
    {
        const int ix0 = x0a[p], iy0 = y0a[p], ix1 = x1a[p], iy1 = y1a[p];
        const float2 w2 = *(const float2*)(lerp_w + 2 * p);
        const float wx = w2.x, wy = w2.y;
        const float w00 = (1.0f - wx) * (1.0f - wy);
        const float w01 = wx * (1.0f - wy);
        const float w10 = (1.0f - wx) * wy;
        const float w11 = wx * wy;
        const f32x4* c00 = (const f32x4*)(data + (iy0 * 512 + ix0) * 32);
        const f32x4* c01 = (const f32x4*)(data + (iy0 * 512 + ix1) * 32);
        const f32x4* c10 = (const f32x4*)(data + (iy1 * 512 + ix0) * 32);
        const f32x4* c11 = (const f32x4*)(data + (iy1 * 512 + ix1) * 32);
#pragma unroll
        for (int q = 0; q < 8; ++q)
            fq[q] = c00[q] * w00 + c01[q] * w01 + c10[q] * w10 + c11[q] * w11;
    }

    const f32x2* W1v = (const f32x2*)W1;      // [32][16] float2
    const f32x2* W2v = (const f32x2*)W2;
    const f32x2* W3v = (const f32x2*)W3;      // [16] float2
    const f32x2* b1v = (const f32x2*)b1;
    const f32x2* b2v = (const f32x2*)b2;
    const f32x2 zero2 = (f32x2)(0.0f);

    // Batch loop rolled (code size); layers fully unrolled so weight
    // addresses are uniform compile-time offsets -> scalar fetches.
#pragma unroll 1
    for (int b = 0; b < 8; ++b) {
        // ---- Layer 1: h = relu(W1^T (f .* zf_b) + b1), j packed in pairs ----
        f32x2 h2[16];
#pragma unroll
        for (int k = 0; k < 16; ++k) h2[k] = b1v[k];
#pragma unroll
        for (int i = 0; i < 32; ++i) {
            const float zf = zf_lds[b][i];    // wave-uniform LDS broadcast
            const float va = fq[i >> 2][i & 3] * zf;
            const f32x2 va2 = { va, va };
#pragma unroll
            for (int k = 0; k < 16; ++k)
                h2[k] = __builtin_elementwise_fma(va2, W1v[i * 16 + k], h2[k]);
        }
#pragma unroll
        for (int k = 0; k < 16; ++k)
            h2[k] = __builtin_elementwise_max(h2[k], zero2);

        // ---- Layer 2 ----
        f32x2 g2[16];
#pragma unroll
        for (int k = 0; k < 16; ++k) g2[k] = b2v[k];
#pragma unroll
        for (int i = 0; i < 32; ++i) {
            const float va = h2[i >> 1][i & 1];
            const f32x2 va2 = { va, va };
#pragma unroll
            for (int k = 0; k < 16; ++k)
                g2[k] = __builtin_elementwise_fma(va2, W2v[i * 16 + k], g2[k]);
        }

        // ---- Layer 3: out = relu(g) . W3 + b3 ----
        f32x2 acc2 = { b3[0], 0.0f };
#pragma unroll
        for (int k = 0; k < 16; ++k) {
            const f32x2 gr = __builtin_elementwise_max(g2[k], zero2);
            acc2 = __builtin_elementwise_fma(gr, W3v[k], acc2);
        }

        // Write-once 8 MB stream: nontemporal keeps it out of L2.
        __builtin_nontemporal_store(acc2[0] + acc2[1], out + b * NPIX + p);
    }
}

extern "C" void kernel_launch(void* const* d_in, const int* in_sizes, int n_in,
                              void* d_out, int out_size, void* d_ws, size_t ws_size,
                              hipStream_t stream) {
    const float* zp      = (const float*)d_in[0];
    const float* data    = (const float*)d_in[1];
    const float* z_data  = (const float*)d_in[2];
    const float* lerp_w  = (const float*)d_in[3];
    const int*   x0      = (const int*)d_in[4];
    const int*   y0      = (const int*)d_in[5];
    const int*   x1      = (const int*)d_in[6];
    const int*   y1      = (const int*)d_in[7];
    const float* W1      = (const float*)d_in[8];
    const float* b1      = (const float*)d_in[9];
    const float* W2      = (const float*)d_in[10];
    const float* b2      = (const float*)d_in[11];
    const float* W3      = (const float*)d_in[12];
    const float* b3      = (const float*)d_in[13];
    float* out = (float*)d_out;

    dim3 grid(NPIX / 256);   // 1024 blocks = 4 blocks/CU exactly
    dim3 block(256);
    hipLaunchKernelGGL(field_mlp_kernel, grid, block, 0, stream,
                       zp, data, z_data, lerp_w, x0, y0, x1, y1,
                       W1, b1, W2, b2, W3, b3, out);
}

// Round 4
// 175.891 us; speedup vs baseline: 1.9129x; 1.9129x over previous
//
#include <hip/hip_runtime.h>

// Fused tensor-field + 3-layer MLP for MI355X (gfx950). Round 4.
//
// R3 post-mortem: __launch_bounds__(256,4) min-waves hint made regalloc
// target 8 waves/SIMD -> 64 VGPRs vs ~100 live floats -> 148 B/thread of
// scratch spills (WRITE_SIZE 46MB vs 8.2MB stored). VALU issue 191us vs
// 55us FMA floor = spill bloat.
//
// Fix: eliminate long-lived per-thread state. One thread = one (pixel,batch)
// work item; 32 px x 8 batches per 256-thread block. Bilinear feature f[32]
// gathered cooperatively ONCE per block into LDS (thread=(px,chunk): 4x
// float4 corner loads -> combine -> ds_write; no idle lanes, no redundancy).
// f stored transposed [feat][px] (pad 33): MLP reads are conflict-free
// ds_read_b32 with single base + imm offset. Per-thread live state is just
// h2/g2 (64 VGPR) + temps ~= 85 peak; __launch_bounds__(256) with NO
// min-waves hint -> 256-VGPR cap, no spill pressure.
// Falsifiable signature: WRITE_SIZE drops to ~8192 KB exactly.

typedef float f32x2 __attribute__((ext_vector_type(2)));
typedef float f32x4 __attribute__((ext_vector_type(4)));

constexpr int NPIX = 512 * 512;
constexpr int PPB  = 32;            // pixels per block

__global__ __launch_bounds__(256) void field_mlp_kernel(
    const float* __restrict__ z,        // [8]
    const float* __restrict__ data,     // [512,512,32]
    const float* __restrict__ z_data,   // [64,32]
    const float* __restrict__ lerp_w,   // [NPIX,2]
    const int* __restrict__ x0a, const int* __restrict__ y0a,
    const int* __restrict__ x1a, const int* __restrict__ y1a,
    const float* __restrict__ W1, const float* __restrict__ b1,
    const float* __restrict__ W2, const float* __restrict__ b2,
    const float* __restrict__ W3, const float* __restrict__ b3,
    float* __restrict__ out)            // [8,1,512,512]
{
    __shared__ float f_lds[32][PPB + 1];   // [feat][pixel], padded
    __shared__ float zf_lds[8][33];        // z-feature per batch, padded

    const int tid = threadIdx.x;

    // ---- z-feature: 256 threads = 8 batches x 32 feats ----
    {
        const int b = tid >> 5;
        const int i = tid & 31;
        const float zn = 63.0f * z[b];        // Z_MIN=0, Z_MAX=1
        int z0 = (int)zn;
        z0 = max(0, min(z0, 63));
        const int z1 = min(z0 + 1, 63);
        const float zl = zn - truncf(zn);
        zf_lds[b][i] = z_data[z0 * 32 + i] * (1.0f - zl) + z_data[z1 * 32 + i] * zl;
    }

    // ---- cooperative bilinear gather: thread = (px, 4-feat chunk) ----
    {
        const int pxl = tid >> 3;             // 0..31
        const int ch  = tid & 7;              // 0..7
        const int p   = blockIdx.x * PPB + pxl;
        const int ix0 = x0a[p], iy0 = y0a[p], ix1 = x1a[p], iy1 = y1a[p];
        const float2 w2 = *(const float2*)(lerp_w + 2 * p);
        const float wx = w2.x, wy = w2.y;
        const float w00 = (1.0f - wx) * (1.0f - wy);
        const float w01 = wx * (1.0f - wy);
        const float w10 = (1.0f - wx) * wy;
        const float w11 = wx * wy;
        const f32x4* base = (const f32x4*)data;      // cell stride = 8 chunks
        const f32x4 c00 = base[(iy0 * 512 + ix0) * 8 + ch];
        const f32x4 c01 = base[(iy0 * 512 + ix1) * 8 + ch];
        const f32x4 c10 = base[(iy1 * 512 + ix0) * 8 + ch];
        const f32x4 c11 = base[(iy1 * 512 + ix1) * 8 + ch];
        const f32x4 v = c00 * w00 + c01 * w01 + c10 * w10 + c11 * w11;
#pragma unroll
        for (int j = 0; j < 4; ++j)
            f_lds[ch * 4 + j][pxl] = v[j];    // transposed store
    }
    __syncthreads();

    // ---- MLP: thread = (px, batch) ----
    const int pxl = tid & 31;
    const int b   = tid >> 5;
    const int p   = blockIdx.x * PPB + pxl;

    const f32x2* W1v = (const f32x2*)W1;      // [32][16] float2
    const f32x2* W2v = (const f32x2*)W2;
    const f32x2* W3v = (const f32x2*)W3;      // [16] float2
    const f32x2* b1v = (const f32x2*)b1;
    const f32x2* b2v = (const f32x2*)b2;
    const f32x2 zero2 = (f32x2)(0.0f);

    // Layer 1: h = relu(W1^T (f .* zf_b) + b1)
    f32x2 h2[16];
#pragma unroll
    for (int k = 0; k < 16; ++k) h2[k] = b1v[k];
#pragma unroll
    for (int i = 0; i < 32; ++i) {
        const float v = f_lds[i][pxl] * zf_lds[b][i];   // conflict-free ds_read
        const f32x2 v2 = { v, v };
#pragma unroll
        for (int k = 0; k < 16; ++k)
            h2[k] = __builtin_elementwise_fma(v2, W1v[i * 16 + k], h2[k]);
    }
#pragma unroll
    for (int k = 0; k < 16; ++k)
        h2[k] = __builtin_elementwise_max(h2[k], zero2);

    // Layer 2
    f32x2 g2[16];
#pragma unroll
    for (int k = 0; k < 16; ++k) g2[k] = b2v[k];
#pragma unroll
    for (int i = 0; i < 32; ++i) {
        const float v = h2[i >> 1][i & 1];
        const f32x2 v2 = { v, v };
#pragma unroll
        for (int k = 0; k < 16; ++k)
            g2[k] = __builtin_elementwise_fma(v2, W2v[i * 16 + k], g2[k]);
    }

    // Layer 3: out = relu(g) . W3 + b3
    f32x2 acc2 = { b3[0], 0.0f };
#pragma unroll
    for (int k = 0; k < 16; ++k) {
        const f32x2 gr = __builtin_elementwise_max(g2[k], zero2);
        acc2 = __builtin_elementwise_fma(gr, W3v[k], acc2);
    }

    __builtin_nontemporal_store(acc2[0] + acc2[1], out + b * NPIX + p);
}

extern "C" void kernel_launch(void* const* d_in, const int* in_sizes, int n_in,
                              void* d_out, int out_size, void* d_ws, size_t ws_size,
                              hipStream_t stream) {
    const float* zp      = (const float*)d_in[0];
    const float* data    = (const float*)d_in[1];
    const float* z_data  = (const float*)d_in[2];
    const float* lerp_w  = (const float*)d_in[3];
    const int*   x0      = (const int*)d_in[4];
    const int*   y0      = (const int*)d_in[5];
    const int*   x1      = (const int*)d_in[6];
    const int*   y1      = (const int*)d_in[7];
    const float* W1      = (const float*)d_in[8];
    const float* b1      = (const float*)d_in[9];
    const float* W2      = (const float*)d_in[10];
    const float* b2      = (const float*)d_in[11];
    const float* W3      = (const float*)d_in[12];
    const float* b3      = (const float*)d_in[13];
    float* out = (float*)d_out;

    dim3 grid(NPIX / PPB);   // 8192 blocks
    dim3 block(256);
    hipLaunchKernelGGL(field_mlp_kernel, grid, block, 0, stream,
                       zp, data, z_data, lerp_w, x0, y0, x1, y1,
                       W1, b1, W2, b2, W3, b3, out);
}

// Round 6
// 147.842 us; speedup vs baseline: 2.2758x; 1.1897x over previous
//
#include <hip/hip_runtime.h>

// Fused tensor-field + 3-layer MLP for MI355X (gfx950). Round 5 resubmit: MFMA.
//
// R4 post-mortem: f32 path at 97us vs 55us hard VALU floor (CDNA4 FP32 spec
// 157.3 TF IS the scalar SIMD-32 rate; packed f32 adds nothing, no fp32 MFMA).
// Only >=2x lever: bf16 matrix pipe (2.5 PF). Per block (32px x 8b = 256 rows):
// L1/L2 are M=256,N=32,K=32 GEMMs -> 16x16x32_bf16 MFMA, 3-term hi/lo split
// (Ah*Bh + Ah*Bl + Al*Bh; truncation split, residual exact) ~ f32 accuracy.
// Layouts: A-frag m=lane&15, k=(lane>>4)*8+j; B-frag mirrored; C/D col=lane&15,
// row=(lane>>4)*4+reg [m89]. W^T in LDS, pad-40-bf16 rows (16B aligned,
// conflict-free b128 frags). h via LDS f32 [256][33] pad. Wave owns rows
// w*64..+63 -> all post-gather barriers are safety-only.

typedef float f32x4 __attribute__((ext_vector_type(4)));
typedef short bf16x8 __attribute__((ext_vector_type(8)));

constexpr int NPIX = 512 * 512;
constexpr int PPB  = 32;   // pixels per block; rows = 32px * 8batch = 256
constexpr int WROW = 20;   // uints per W^T row = 40 bf16 (32 + 8 pad)

union FragU { unsigned int u[4]; uint4 v; bf16x8 s; };

// result[15:0] = top16 bits of e0 (bf16-truncate), result[31:16] = top16 of e1
__device__ __forceinline__ unsigned int pack_top16(float e0, float e1) {
    return __builtin_amdgcn_perm(__float_as_uint(e1), __float_as_uint(e0), 0x07060302u);
}
__device__ __forceinline__ float trunc_bf16(float x) {
    return __uint_as_float(__float_as_uint(x) & 0xFFFF0000u);
}

__global__ __launch_bounds__(256) void field_mlp_mfma(
    const float* __restrict__ z,        // [8]
    const float* __restrict__ data,     // [512,512,32]
    const float* __restrict__ z_data,   // [64,32]
    const float* __restrict__ lerp_w,   // [NPIX,2]
    const int* __restrict__ x0a, const int* __restrict__ y0a,
    const int* __restrict__ x1a, const int* __restrict__ y1a,
    const float* __restrict__ W1, const float* __restrict__ b1,
    const float* __restrict__ W2, const float* __restrict__ b2,
    const float* __restrict__ W3, const float* __restrict__ b3,
    float* __restrict__ out)            // [8,1,512,512]
{
    __shared__ float f_lds[32][PPB + 1];                 // [feat][px]
    __shared__ float zf_lds[8][33];                      // [batch][feat]
    __shared__ float bias_lds[2][32];                    // b1, b2
    __shared__ __align__(16) unsigned int wt_lds[4][32][WROW]; // W1h,W1l,W2h,W2l as [n][k] bf16x2
    __shared__ float h_lds[256][33];                     // activations f32

    const int tid = threadIdx.x;

    // ---- z-feature: 8 batches x 32 feats ----
    {
        const int b = tid >> 5, i = tid & 31;
        const float zn = 63.0f * z[b];
        int z0 = (int)zn; z0 = max(0, min(z0, 63));
        const int z1i = min(z0 + 1, 63);
        const float zl = zn - truncf(zn);
        zf_lds[b][i] = z_data[z0 * 32 + i] * (1.0f - zl) + z_data[z1i * 32 + i] * zl;
    }
    // ---- biases to LDS ----
    if (tid < 64) bias_lds[tid >> 5][tid & 31] = (tid < 32) ? b1[tid] : b2[tid & 31];

    // ---- cooperative bilinear gather: thread = (px, 4-feat chunk) ----
    {
        const int pxl = tid >> 3, ch = tid & 7;
        const int p = blockIdx.x * PPB + pxl;
        const int ix0 = x0a[p], iy0 = y0a[p], ix1 = x1a[p], iy1 = y1a[p];
        const float2 w2 = *(const float2*)(lerp_w + 2 * p);
        const float wx = w2.x, wy = w2.y;
        const float w00 = (1.0f - wx) * (1.0f - wy);
        const float w01 = wx * (1.0f - wy);
        const float w10 = (1.0f - wx) * wy;
        const float w11 = wx * wy;
        const f32x4* base = (const f32x4*)data;
        const f32x4 c00 = base[(iy0 * 512 + ix0) * 8 + ch];
        const f32x4 c01 = base[(iy0 * 512 + ix1) * 8 + ch];
        const f32x4 c10 = base[(iy1 * 512 + ix0) * 8 + ch];
        const f32x4 c11 = base[(iy1 * 512 + ix1) * 8 + ch];
        const f32x4 v = c00 * w00 + c01 * w01 + c10 * w10 + c11 * w11;
#pragma unroll
        for (int j = 0; j < 4; ++j) f_lds[ch * 4 + j][pxl] = v[j];
    }

    // ---- W1/W2 transpose + hi/lo split into LDS: thread = (n, 4-k chunk) ----
    {
        const int n = tid & 31, kc = (tid >> 5) * 4, kw = (tid >> 5) * 2;
#pragma unroll
        for (int m = 0; m < 2; ++m) {
            const float* Wm = m ? W2 : W1;
            const float x0 = Wm[(kc + 0) * 32 + n];
            const float x1 = Wm[(kc + 1) * 32 + n];
            const float x2 = Wm[(kc + 2) * 32 + n];
            const float x3 = Wm[(kc + 3) * 32 + n];
            wt_lds[2 * m][n][kw]     = pack_top16(x0, x1);
            wt_lds[2 * m][n][kw + 1] = pack_top16(x2, x3);
            wt_lds[2 * m + 1][n][kw]     = pack_top16(x0 - trunc_bf16(x0), x1 - trunc_bf16(x1));
            wt_lds[2 * m + 1][n][kw + 1] = pack_top16(x2 - trunc_bf16(x2), x3 - trunc_bf16(x3));
        }
    }
    __syncthreads();

    const int w  = tid >> 6;          // wave id: owns rows w*64 .. w*64+63
    const int l  = tid & 63;
    const int lg = l >> 4, lr = l & 15;

    // Hoist the lane's f / zf slices (reused across tiles)
    float fv0[8], fv1[8], zv0[8], zv1[8];
#pragma unroll
    for (int j = 0; j < 8; ++j) {
        const int i = lg * 8 + j;
        fv0[j] = f_lds[i][lr];
        fv1[j] = f_lds[i][16 + lr];
        zv0[j] = zf_lds[2 * w][i];
        zv1[j] = zf_lds[2 * w + 1][i];
    }

    const f32x4 vzero = {0.0f, 0.0f, 0.0f, 0.0f};
    f32x4 acc[4][2];
#pragma unroll
    for (int tm = 0; tm < 4; ++tm) { acc[tm][0] = vzero; acc[tm][1] = vzero; }

    auto gemm_tile = [&](const float (&ev)[8], const FragU (&BH)[2],
                         const FragU (&BL)[2], f32x4 (&ar)[2]) {
        FragU Ah, Al;
#pragma unroll
        for (int r = 0; r < 4; ++r) {
            const float x0 = ev[2 * r], x1 = ev[2 * r + 1];
            Ah.u[r] = pack_top16(x0, x1);
            Al.u[r] = pack_top16(x0 - trunc_bf16(x0), x1 - trunc_bf16(x1));
        }
#pragma unroll
        for (int tn = 0; tn < 2; ++tn) {
            ar[tn] = __builtin_amdgcn_mfma_f32_16x16x32_bf16(Al.s, BH[tn].s, ar[tn], 0, 0, 0);
            ar[tn] = __builtin_amdgcn_mfma_f32_16x16x32_bf16(Ah.s, BL[tn].s, ar[tn], 0, 0, 0);
            ar[tn] = __builtin_amdgcn_mfma_f32_16x16x32_bf16(Ah.s, BH[tn].s, ar[tn], 0, 0, 0);
        }
    };

    // ---- Layer 1 ----
    {
        FragU BH[2], BL[2];
#pragma unroll
        for (int tn = 0; tn < 2; ++tn) {
            BH[tn].v = *(const uint4*)&wt_lds[0][tn * 16 + lr][lg * 4];
            BL[tn].v = *(const uint4*)&wt_lds[1][tn * 16 + lr][lg * 4];
        }
        float e[8];
#pragma unroll
        for (int j = 0; j < 8; ++j) e[j] = fv0[j] * zv0[j];   // tile0: px=lr,    b=2w
        gemm_tile(e, BH, BL, acc[0]);
#pragma unroll
        for (int j = 0; j < 8; ++j) e[j] = fv1[j] * zv0[j];   // tile1: px=16+lr, b=2w
        gemm_tile(e, BH, BL, acc[1]);
#pragma unroll
        for (int j = 0; j < 8; ++j) e[j] = fv0[j] * zv1[j];   // tile2: px=lr,    b=2w+1
        gemm_tile(e, BH, BL, acc[2]);
#pragma unroll
        for (int j = 0; j < 8; ++j) e[j] = fv1[j] * zv1[j];   // tile3: px=16+lr, b=2w+1
        gemm_tile(e, BH, BL, acc[3]);
    }
    // epilogue: h = relu(acc + b1) -> h_lds
    {
        const float bb0 = bias_lds[0][lr], bb1 = bias_lds[0][16 + lr];
#pragma unroll
        for (int tm = 0; tm < 4; ++tm)
#pragma unroll
            for (int tn = 0; tn < 2; ++tn) {
                const float bb = tn ? bb1 : bb0;
#pragma unroll
                for (int r = 0; r < 4; ++r) {
                    const int row = w * 64 + tm * 16 + lg * 4 + r;
                    h_lds[row][tn * 16 + lr] = fmaxf(acc[tm][tn][r] + bb, 0.0f);
                }
            }
    }
    __syncthreads();   // safety (rows are wave-private)

    // ---- Layer 2 ----
#pragma unroll
    for (int tm = 0; tm < 4; ++tm) { acc[tm][0] = vzero; acc[tm][1] = vzero; }
    {
        FragU BH[2], BL[2];
#pragma unroll
        for (int tn = 0; tn < 2; ++tn) {
            BH[tn].v = *(const uint4*)&wt_lds[2][tn * 16 + lr][lg * 4];
            BL[tn].v = *(const uint4*)&wt_lds[3][tn * 16 + lr][lg * 4];
        }
        float e[8];
#pragma unroll
        for (int tm = 0; tm < 4; ++tm) {
            const int row = w * 64 + tm * 16 + lr;
#pragma unroll
            for (int j = 0; j < 8; ++j) e[j] = h_lds[row][lg * 8 + j];
            gemm_tile(e, BH, BL, acc[tm]);
        }
    }
    __syncthreads();   // all L2 A-frag reads done before in-place overwrite
    // epilogue: g_relu = relu(acc + b2) -> h_lds (in place)
    {
        const float bb0 = bias_lds[1][lr], bb1 = bias_lds[1][16 + lr];
#pragma unroll
        for (int tm = 0; tm < 4; ++tm)
#pragma unroll
            for (int tn = 0; tn < 2; ++tn) {
                const float bb = tn ? bb1 : bb0;
#pragma unroll
                for (int r = 0; r < 4; ++r) {
                    const int row = w * 64 + tm * 16 + lg * 4 + r;
                    h_lds[row][tn * 16 + lr] = fmaxf(acc[tm][tn][r] + bb, 0.0f);
                }
            }
    }
    __syncthreads();

    // ---- Layer 3: out = relu(g) . W3 + b3 (row-owner thread) ----
    {
        float accum = b3[0];
#pragma unroll
        for (int jj = 0; jj < 32; ++jj)
            accum = fmaf(h_lds[tid][jj], W3[jj], accum);
        const int b = tid >> 5, px = tid & 31;
        __builtin_nontemporal_store(accum, out + b * NPIX + blockIdx.x * PPB + px);
    }
}

extern "C" void kernel_launch(void* const* d_in, const int* in_sizes, int n_in,
                              void* d_out, int out_size, void* d_ws, size_t ws_size,
                              hipStream_t stream) {
    const float* zp      = (const float*)d_in[0];
    const float* data    = (const float*)d_in[1];
    const float* z_data  = (const float*)d_in[2];
    const float* lerp_w  = (const float*)d_in[3];
    const int*   x0      = (const int*)d_in[4];
    const int*   y0      = (const int*)d_in[5];
    const int*   x1      = (const int*)d_in[6];
    const int*   y1      = (const int*)d_in[7];
    const float* W1      = (const float*)d_in[8];
    const float* b1      = (const float*)d_in[9];
    const float* W2      = (const float*)d_in[10];
    const float* b2      = (const float*)d_in[11];
    const float* W3      = (const float*)d_in[12];
    const float* b3      = (const float*)d_in[13];
    float* out = (float*)d_out;

    dim3 grid(NPIX / PPB);   // 8192 blocks
    dim3 block(256);
    hipLaunchKernelGGL(field_mlp_mfma, grid, block, 0, stream,
                       zp, data, z_data, lerp_w, x0, y0, x1, y1,
                       W1, b1, W2, b2, W3, b3, out);
}

// Round 8
// 128.693 us; speedup vs baseline: 2.6145x; 1.1488x over previous
//
#include <hip/hip_runtime.h>

// Fused tensor-field + 3-layer MLP for MI355X (gfx950). Round 7 resubmit.
//
// R6 post-mortem: 60us, LDS-throughput-bound: ~160 scalar LDS ops/thread
// (h round-trip + scalar epilogues) ~= 58us of LDS-unit time/CU, plus 8.9M
// bank-conflict cycles. MFMA pipe only ~10us.
//
// This round: h NEVER touches LDS. Transposed formulation (W = A operand,
// activations = B operand; D[n][m], col=lane&15=m). L1 output tiles use
// sigma-striped n-assignment sigma(p)=8*(p>>2)+(p&3) (+4 for tile B) so lane
// lg's accumulators hold exactly h[8lg..8lg+7] = L2's B-frag k-run. L1->L2 is
// 8 packs, zero cross-lane. L3 = in-register dot + 2 shfl_xor. All remaining
// LDS traffic (f, zf, W-frags, biases) is b128 on pad-36 rows, conflict-light.
// PPB=64: per wave 8 m-tiles, weight frags loaded once. L1 uses 2-term split
// (e ~ 1e-4 -> dropped el*W ~ 6e-7 abs, negligible); L2 keeps 3-term.

typedef float f32x4 __attribute__((ext_vector_type(4)));
typedef short bf16x8 __attribute__((ext_vector_type(8)));

constexpr int NPIX = 512 * 512;
constexpr int PPB  = 64;    // pixels per block; rows = 8 batches x 64 px = 512

union FragU { unsigned int u[4]; uint4 v; bf16x8 s; };

// D[15:0] = top16 of e0 (bf16 truncate), D[31:16] = top16 of e1
__device__ __forceinline__ unsigned int pack_top16(float e0, float e1) {
    return __builtin_amdgcn_perm(__float_as_uint(e1), __float_as_uint(e0), 0x07060302u);
}
__device__ __forceinline__ float trunc_bf16(float x) {
    return __uint_as_float(__float_as_uint(x) & 0xFFFF0000u);
}

__global__ __launch_bounds__(256) void field_mlp_mfma3(
    const float* __restrict__ z,        // [8]
    const float* __restrict__ data,     // [512,512,32]
    const float* __restrict__ z_data,   // [64,32]
    const float* __restrict__ lerp_w,   // [NPIX,2]
    const int* __restrict__ x0a, const int* __restrict__ y0a,
    const int* __restrict__ x1a, const int* __restrict__ y1a,
    const float* __restrict__ W1, const float* __restrict__ b1,
    const float* __restrict__ W2, const float* __restrict__ b2,
    const float* __restrict__ W3, const float* __restrict__ b3,
    float* __restrict__ out)            // [8,1,512,512]
{
    __shared__ float f_T[PPB][36];                       // [px][feat], pad 36
    __shared__ float zf_lds[8][36];                      // [batch][feat]
    __shared__ float bias_lds[2][36];                    // b1, b2
    __shared__ float w3_lds[36];
    __shared__ __align__(16) unsigned int wt_lds[4][32][20]; // W1h,W1l,W2h,W2l [n][k-pairs]

    const int tid = threadIdx.x;

    // ---- z-feature: 8 batches x 32 feats ----
    {
        const int b = tid >> 5, i = tid & 31;
        const float zn = 63.0f * z[b];               // Z_MIN=0, Z_MAX=1
        int z0 = (int)zn; z0 = max(0, min(z0, 63));
        const int z1i = min(z0 + 1, 63);
        const float zl = zn - truncf(zn);
        zf_lds[b][i] = z_data[z0 * 32 + i] * (1.0f - zl) + z_data[z1i * 32 + i] * zl;
    }
    // ---- biases / w3 ----
    if (tid < 32) {
        bias_lds[0][tid] = b1[tid];
        bias_lds[1][tid] = b2[tid];
        w3_lds[tid]      = W3[tid];
    }
    // ---- cooperative bilinear gather: 2 units/thread, unit = (px, 4-feat chunk) ----
#pragma unroll
    for (int u = 0; u < 2; ++u) {
        const int unit = tid + u * 256;
        const int pxl = unit >> 3, ch = unit & 7;
        const int p = blockIdx.x * PPB + pxl;
        const int ix0 = x0a[p], iy0 = y0a[p], ix1 = x1a[p], iy1 = y1a[p];
        const float2 w2 = *(const float2*)(lerp_w + 2 * p);
        const float wx = w2.x, wy = w2.y;
        const float w00 = (1.0f - wx) * (1.0f - wy);
        const float w01 = wx * (1.0f - wy);
        const float w10 = (1.0f - wx) * wy;
        const float w11 = wx * wy;
        const f32x4* base = (const f32x4*)data;
        const f32x4 c00 = base[(iy0 * 512 + ix0) * 8 + ch];
        const f32x4 c01 = base[(iy0 * 512 + ix1) * 8 + ch];
        const f32x4 c10 = base[(iy1 * 512 + ix0) * 8 + ch];
        const f32x4 c11 = base[(iy1 * 512 + ix1) * 8 + ch];
        const f32x4 v = c00 * w00 + c01 * w01 + c10 * w10 + c11 * w11;
        *(f32x4*)&f_T[pxl][ch * 4] = v;              // b128 write
    }
    // ---- W1/W2 transpose + hi/lo split: thread = (n, 4-k chunk) ----
    {
        const int n = tid & 31, kc = (tid >> 5) * 4, kw = (tid >> 5) * 2;
#pragma unroll
        for (int m = 0; m < 2; ++m) {
            const float* Wm = m ? W2 : W1;
            const float x0 = Wm[(kc + 0) * 32 + n];
            const float x1 = Wm[(kc + 1) * 32 + n];
            const float x2 = Wm[(kc + 2) * 32 + n];
            const float x3 = Wm[(kc + 3) * 32 + n];
            wt_lds[2 * m][n][kw]     = pack_top16(x0, x1);
            wt_lds[2 * m][n][kw + 1] = pack_top16(x2, x3);
            wt_lds[2 * m + 1][n][kw]     = pack_top16(x0 - trunc_bf16(x0), x1 - trunc_bf16(x1));
            wt_lds[2 * m + 1][n][kw + 1] = pack_top16(x2 - trunc_bf16(x2), x3 - trunc_bf16(x3));
        }
    }
    __syncthreads();

    const int l  = tid & 63, w = tid >> 6;           // wave handles batches 2w, 2w+1
    const int lg = l >> 4,  lr = l & 15;
    const int srow = ((lr >> 2) << 3) + (lr & 3);    // sigma-stripe row for W1 tiles

    // ---- preload fragments (reused across all m-tiles) ----
    FragU W1f[2][2], W2f[2][2];                      // [tile][hi=0/lo=1]
#pragma unroll
    for (int t = 0; t < 2; ++t) {
        W1f[t][0].v = *(const uint4*)&wt_lds[0][srow + 4 * t][lg * 4];
        W1f[t][1].v = *(const uint4*)&wt_lds[1][srow + 4 * t][lg * 4];
        W2f[t][0].v = *(const uint4*)&wt_lds[2][t * 16 + lr][lg * 4];
        W2f[t][1].v = *(const uint4*)&wt_lds[3][t * 16 + lr][lg * 4];
    }
    f32x4 zva[2], zvb[2], b1v[2], b2v[2], w3v[2];
#pragma unroll
    for (int bb = 0; bb < 2; ++bb) {
        zva[bb] = *(const f32x4*)&zf_lds[2 * w + bb][lg * 8];
        zvb[bb] = *(const f32x4*)&zf_lds[2 * w + bb][lg * 8 + 4];
    }
#pragma unroll
    for (int t = 0; t < 2; ++t) {
        b1v[t] = *(const f32x4*)&bias_lds[0][8 * lg + 4 * t];   // sigma-striped n
        b2v[t] = *(const f32x4*)&bias_lds[1][t * 16 + 4 * lg];
        w3v[t] = *(const f32x4*)&w3_lds[t * 16 + 4 * lg];
    }
    const float b3s = b3[0];
    const f32x4 vzero = {0.0f, 0.0f, 0.0f, 0.0f};
    float* const outp = out + blockIdx.x * PPB;

#pragma unroll
    for (int pxg = 0; pxg < 4; ++pxg) {
        const int px = pxg * 16 + lr;                // this lane's pixel (as B-col)
        const f32x4 ff0 = *(const f32x4*)&f_T[px][lg * 8];
        const f32x4 ff1 = *(const f32x4*)&f_T[px][lg * 8 + 4];
#pragma unroll
        for (int bb = 0; bb < 2; ++bb) {
            // e^T B-frag: e = f .* zf (f32), truncate-pack hi only (2-term L1)
            const f32x4 ea = ff0 * zva[bb];
            const f32x4 eb = ff1 * zvb[bb];
            FragU Eh;
            Eh.u[0] = pack_top16(ea[0], ea[1]);
            Eh.u[1] = pack_top16(ea[2], ea[3]);
            Eh.u[2] = pack_top16(eb[0], eb[1]);
            Eh.u[3] = pack_top16(eb[2], eb[3]);
            // L1: h^T tiles (sigma-striped): acc[t] reg r holds n = 8lg + r + 4t
            f32x4 hv[2];
#pragma unroll
            for (int t = 0; t < 2; ++t) {
                f32x4 a = __builtin_amdgcn_mfma_f32_16x16x32_bf16(W1f[t][1].s, Eh.s, vzero, 0, 0, 0);
                a = __builtin_amdgcn_mfma_f32_16x16x32_bf16(W1f[t][0].s, Eh.s, a, 0, 0, 0);
                a = a + b1v[t];
#pragma unroll
                for (int r = 0; r < 4; ++r) a[r] = fmaxf(a[r], 0.0f);
                hv[t] = a;
            }
            // lane now holds h[8lg .. 8lg+7] = L2 B-frag k-run. Split hi/lo.
            FragU Hh, Hl;
            Hh.u[0] = pack_top16(hv[0][0], hv[0][1]);
            Hh.u[1] = pack_top16(hv[0][2], hv[0][3]);
            Hh.u[2] = pack_top16(hv[1][0], hv[1][1]);
            Hh.u[3] = pack_top16(hv[1][2], hv[1][3]);
            f32x4 hl0 = hv[0], hl1 = hv[1];
#pragma unroll
            for (int r = 0; r < 4; ++r) {
                hl0[r] -= trunc_bf16(hv[0][r]);
                hl1[r] -= trunc_bf16(hv[1][r]);
            }
            Hl.u[0] = pack_top16(hl0[0], hl0[1]);
            Hl.u[1] = pack_top16(hl0[2], hl0[3]);
            Hl.u[2] = pack_top16(hl1[0], hl1[1]);
            Hl.u[3] = pack_top16(hl1[2], hl1[3]);
            // L2: 3-term, contiguous n-tiles
            float o = 0.0f;
#pragma unroll
            for (int t = 0; t < 2; ++t) {
                f32x4 a = __builtin_amdgcn_mfma_f32_16x16x32_bf16(W2f[t][0].s, Hl.s, vzero, 0, 0, 0);
                a = __builtin_amdgcn_mfma_f32_16x16x32_bf16(W2f[t][1].s, Hh.s, a, 0, 0, 0);
                a = __builtin_amdgcn_mfma_f32_16x16x32_bf16(W2f[t][0].s, Hh.s, a, 0, 0, 0);
                a = a + b2v[t];
#pragma unroll
                for (int r = 0; r < 4; ++r)
                    o = fmaf(fmaxf(a[r], 0.0f), w3v[t][r], o);
            }
            // L3 reduce across lg groups (lanes lr, lr+16, lr+32, lr+48)
            o += __shfl_xor(o, 16);
            o += __shfl_xor(o, 32);
            o += b3s;
            if (l < 16)
                __builtin_nontemporal_store(o, outp + (2 * w + bb) * NPIX + px);
        }
    }
}

extern "C" void kernel_launch(void* const* d_in, const int* in_sizes, int n_in,
                              void* d_out, int out_size, void* d_ws, size_t ws_size,
                              hipStream_t stream) {
    const float* zp      = (const float*)d_in[0];
    const float* data    = (const float*)d_in[1];
    const float* z_data  = (const float*)d_in[2];
    const float* lerp_w  = (const float*)d_in[3];
    const int*   x0      = (const int*)d_in[4];
    const int*   y0      = (const int*)d_in[5];
    const int*   x1      = (const int*)d_in[6];
    const int*   y1      = (const int*)d_in[7];
    const float* W1      = (const float*)d_in[8];
    const float* b1      = (const float*)d_in[9];
    const float* W2      = (const float*)d_in[10];
    const float* b2      = (const float*)d_in[11];
    const float* W3      = (const float*)d_in[12];
    const float* b3      = (const float*)d_in[13];
    float* out = (float*)d_out;

    dim3 grid(NPIX / PPB);   // 4096 blocks
    dim3 block(256);
    hipLaunchKernelGGL(field_mlp_mfma3, grid, block, 0, stream,
                       zp, data, z_data, lerp_w, x0, y0, x1, y1,
                       W1, b1, W2, b2, W3, b3, out);
}